// Round 4
// baseline (380.031 us; speedup 1.0000x reference)
//
#include <hip/hip_runtime.h>
#include <hip/hip_bf16.h>

#define DD 64
#define NBLK 512  // blocks for k_edgesum; partial = NBLK x 256 x 64 f32

typedef __attribute__((ext_vector_type(8))) short bf16x8_t;
typedef __attribute__((ext_vector_type(4))) float f32x4_t;

__device__ __forceinline__ ushort f2b(float x) {
  __hip_bfloat16 h = __float2bfloat16(x);
  ushort r;
  __builtin_memcpy(&r, &h, 2);
  return r;
}

// ---------------------------------------------------------------------------
// Zero cnt.
// ---------------------------------------------------------------------------
__global__ __launch_bounds__(256) void k_zero(int* __restrict__ p, int n) {
  int gid = blockIdx.x * blockDim.x + threadIdx.x;
  int stride = gridDim.x * blockDim.x;
  for (int i = gid; i < n; i += stride) p[i] = 0;
}

// ---------------------------------------------------------------------------
// Histogram of edge destination nodes (int atomics, L2-resident).
// ---------------------------------------------------------------------------
__global__ __launch_bounds__(256) void k_hist(const int* __restrict__ eidx,
                                              int* __restrict__ cnt, int E) {
  int gid = blockIdx.x * blockDim.x + threadIdx.x;
  int stride = gridDim.x * blockDim.x;
  int E4 = E >> 2;
  const int4* e4 = reinterpret_cast<const int4*>(eidx);
  for (int i = gid; i < E4; i += stride) {
    int4 v = e4[i];
    atomicAdd(&cnt[v.x], 1);
    atomicAdd(&cnt[v.y], 1);
    atomicAdd(&cnt[v.z], 1);
    atomicAdd(&cnt[v.w], 1);
  }
  for (int e = (E4 << 2) + gid; e < E; e += stride) atomicAdd(&cnt[eidx[e]], 1);
}

// ---------------------------------------------------------------------------
// Edge sum directly into per-graph bins: streams edge_attr SEQUENTIALLY,
// scales each row by 1/max(cnt[n],1), LDS-atomic accumulate into acc[graph][d]
// (stride 65 to spread banks: 65%32==1 -> bank = (g + 4*lane16 + i) % 32).
// Each block writes its 256x64 partial to global.
// ---------------------------------------------------------------------------
__global__ __launch_bounds__(512) void k_edgesum(const float* __restrict__ edge_attr,
                                                 const int* __restrict__ eidx,
                                                 const int* __restrict__ cnt,
                                                 const int* __restrict__ batch,
                                                 float* __restrict__ partial, int E) {
  __shared__ float acc[256 * 65];
  int tid = threadIdx.x;
  for (int i = tid; i < 256 * 65; i += 512) acc[i] = 0.f;
  __syncthreads();
  int g = tid >> 4, lane = tid & 15;
  int ggid = blockIdx.x * 32 + g;          // 16-lane group id; consecutive groups
  const int gstride = NBLK * 32;           // -> consecutive edges (coalesced)
  for (int e = ggid; e < E; e += gstride) {
    int n = eidx[e];
    float sc = 1.0f / fmaxf((float)cnt[n], 1.0f);
    int b = batch[n];
    float4 v = *reinterpret_cast<const float4*>(edge_attr + (size_t)e * DD + lane * 4);
    float* dst = &acc[b * 65 + lane * 4];
    atomicAdd(dst + 0, v.x * sc);
    atomicAdd(dst + 1, v.y * sc);
    atomicAdd(dst + 2, v.z * sc);
    atomicAdd(dst + 3, v.w * sc);
  }
  __syncthreads();
  float* out = partial + (size_t)blockIdx.x * (256 * DD);
  for (int i = tid; i < 256 * DD; i += 512) {
    int b = i >> 6, d = i & 63;
    out[i] = acc[b * 65 + d];
  }
}

// ---------------------------------------------------------------------------
// Reduce partials + node->graph x pooling + comb write (bf16 for MFMA MLP).
// One block per graph; batch sorted -> binary search range.
// ---------------------------------------------------------------------------
__global__ __launch_bounds__(256) void k_reduce_pool(const float* __restrict__ partial,
                                                     const float* __restrict__ x,
                                                     const float* __restrict__ u,
                                                     const int* __restrict__ batch,
                                                     ushort* __restrict__ comb, int N) {
  __shared__ int s_lo, s_hi;
  __shared__ float rE[4][64], rV[4][64];
  int b = blockIdx.x;
  int tid = threadIdx.x;
  if (tid == 0) {
    int lo = 0, hi = N;
    while (lo < hi) { int m = (lo + hi) >> 1; if (batch[m] < b) lo = m + 1; else hi = m; }
    s_lo = lo;
    hi = N;
    while (lo < hi) { int m = (lo + hi) >> 1; if (batch[m] < b + 1) lo = m + 1; else hi = m; }
    s_hi = lo;
  }
  __syncthreads();
  int lo = s_lo, hi = s_hi;
  int d = tid & 63, sub = tid >> 6;
  float accE = 0.f, accV = 0.f;
  for (int p = sub; p < NBLK; p += 4)
    accE += partial[(size_t)p * (256 * DD) + b * DD + d];
  for (int n = lo + sub; n < hi; n += 4)
    accV += x[(size_t)n * DD + d];
  rE[sub][d] = accE;
  rV[sub][d] = accV;
  __syncthreads();
  if (sub == 0) {
    float invNb = 1.0f / fmaxf((float)(hi - lo), 1.0f);
    float ue = (rE[0][d] + rE[1][d] + rE[2][d] + rE[3][d]) * invNb;
    float uv = (rV[0][d] + rV[1][d] + rV[2][d] + rV[3][d]) * invNb;
    ushort* row = comb + (size_t)b * 192;
    row[d] = f2b(ue);
    row[64 + d] = f2b(uv);
    row[128 + d] = f2b(u[(size_t)b * DD + d]);
  }
}

// ---------------------------------------------------------------------------
// MFMA MLP: 1 block, 512 threads (8 waves). Each wave owns 32 rows (2 m-tiles
// of 16) x all 4 n-tiles; K stepped by 32 with mfma_f32_16x16x32_bf16.
// Frag layout (verified m92 pattern): A/B lane (l&15)=row, k=(l>>4)*8+i, 8
// contiguous bf16 -> b128 loads; D row=(l>>4)*4+j, col=l&15.
// BN (batch stats) in f32 from LDS hbuf; next-layer input re-cast to bf16.
// ---------------------------------------------------------------------------
template <int K, bool FIRST, bool LAST>
__device__ __forceinline__ void mlp_layer(int tid, const ushort* __restrict__ combg,
                                          float* hbuf, ushort* a_lds, ushort* w_lds,
                                          float* ps, float* pq,
                                          float* bias_s, float* ab, float* bb,
                                          const float* __restrict__ W,
                                          const float* __restrict__ bias,
                                          const float* __restrict__ gamma,
                                          const float* __restrict__ beta,
                                          float* __restrict__ out) {
  const int lane = tid & 63, wv = tid >> 6;
  const int WS = K + 8;  // padded weight row stride (bf16 elems)
  // stage weights bf16: w_lds[n][k] = bf16(W[n*K+k]); W is [64][K] row-major
  for (int i = tid; i < 64 * K; i += 512) {
    int r = i / K, c = i - r * K;
    w_lds[r * WS + c] = f2b(W[i]);
  }
  if (tid < 64) bias_s[tid] = bias[tid];
  __syncthreads();

  f32x4_t acc[2][4];
#pragma unroll
  for (int a = 0; a < 2; ++a)
#pragma unroll
    for (int nt = 0; nt < 4; ++nt) acc[a][nt] = (f32x4_t)(0.0f);

  const int m0 = wv * 32;
  const int r15 = lane & 15, kq = lane >> 4;
  for (int kk = 0; kk < K; kk += 32) {
    int koff = kk + kq * 8;
    bf16x8_t af[2], bf[4];
    if (FIRST) {
      const ushort* ap = combg + (size_t)(m0 + r15) * 192 + koff;
      af[0] = *reinterpret_cast<const bf16x8_t*>(ap);
      af[1] = *reinterpret_cast<const bf16x8_t*>(ap + 16 * 192);
    } else {
      const ushort* ap = &a_lds[(m0 + r15) * 72 + koff];
      af[0] = *reinterpret_cast<const bf16x8_t*>(ap);
      af[1] = *reinterpret_cast<const bf16x8_t*>(ap + 16 * 72);
    }
#pragma unroll
    for (int nt = 0; nt < 4; ++nt)
      bf[nt] = *reinterpret_cast<const bf16x8_t*>(&w_lds[(nt * 16 + r15) * WS + koff]);
#pragma unroll
    for (int a = 0; a < 2; ++a)
#pragma unroll
      for (int nt = 0; nt < 4; ++nt)
        acc[a][nt] = __builtin_amdgcn_mfma_f32_16x16x32_bf16(af[a], bf[nt], acc[a][nt], 0, 0, 0);
  }

  // bias + ReLU, write f32 to hbuf (stride 65)
#pragma unroll
  for (int a = 0; a < 2; ++a) {
#pragma unroll
    for (int nt = 0; nt < 4; ++nt) {
      int col = nt * 16 + r15;
#pragma unroll
      for (int j = 0; j < 4; ++j) {
        int row = m0 + a * 16 + kq * 4 + j;
        float v = acc[a][nt][j] + bias_s[col];
        hbuf[row * 65 + col] = fmaxf(v, 0.f);
      }
    }
  }
  __syncthreads();

  // BN stats: 8 segs x 32 rows
  {
    int col = tid & 63, seg = tid >> 6;
    float s = 0.f, q = 0.f;
#pragma unroll
    for (int t = 0; t < 32; ++t) {
      float v = hbuf[(seg * 32 + t) * 65 + col];
      s += v;
      q += v * v;
    }
    ps[seg * 64 + col] = s;
    pq[seg * 64 + col] = q;
  }
  __syncthreads();
  if (tid < 64) {
    float s = 0.f, q = 0.f;
#pragma unroll
    for (int g = 0; g < 8; ++g) {
      s += ps[g * 64 + tid];
      q += pq[g * 64 + tid];
    }
    float mu = s * (1.0f / 256.0f);
    float var = q * (1.0f / 256.0f) - mu * mu;
    float rs = rsqrtf(var + 1e-5f);
    float A = gamma[tid] * rs;
    ab[tid] = A;
    bb[tid] = beta[tid] - mu * A;
  }
  __syncthreads();
  // apply BN; emit next-layer bf16 input or final f32 output
  for (int i = tid; i < 256 * 64; i += 512) {
    int r = i >> 6, c = i & 63;
    float y = hbuf[r * 65 + c] * ab[c] + bb[c];
    if (LAST)
      out[i] = y;
    else
      a_lds[r * 72 + c] = f2b(y);
  }
  __syncthreads();
}

__global__ __launch_bounds__(512) void k_mlp(const ushort* __restrict__ comb,
                                             const float* W0, const float* b0,
                                             const float* W1, const float* b1,
                                             const float* W2, const float* b2,
                                             const float* g0, const float* be0,
                                             const float* g1, const float* be1,
                                             const float* g2, const float* be2,
                                             float* __restrict__ out) {
  __shared__ float hbuf[256 * 65];    // 66.6 KB
  __shared__ ushort a_lds[256 * 72];  // 36.9 KB
  __shared__ ushort w_lds[64 * 200];  // 25.6 KB (max: K=192)
  __shared__ float ps[8 * 64], pq[8 * 64];
  __shared__ float bias_s[64], ab[64], bb[64];
  int tid = threadIdx.x;
  mlp_layer<192, true, false>(tid, comb, hbuf, a_lds, w_lds, ps, pq, bias_s, ab, bb,
                              W0, b0, g0, be0, nullptr);
  mlp_layer<64, false, false>(tid, comb, hbuf, a_lds, w_lds, ps, pq, bias_s, ab, bb,
                              W1, b1, g1, be1, nullptr);
  mlp_layer<64, false, true>(tid, comb, hbuf, a_lds, w_lds, ps, pq, bias_s, ab, bb,
                             W2, b2, g2, be2, out);
}

extern "C" void kernel_launch(void* const* d_in, const int* in_sizes, int n_in,
                              void* d_out, int out_size, void* d_ws, size_t ws_size,
                              hipStream_t stream) {
  (void)n_in; (void)out_size; (void)ws_size;
  const float* x         = (const float*)d_in[0];
  const float* edge_attr = (const float*)d_in[1];
  const float* u         = (const float*)d_in[2];
  const int*   eidx      = (const int*)d_in[3];  // row 0 = first E entries
  const int*   batch     = (const int*)d_in[4];
  const float* W0 = (const float*)d_in[5];
  const float* b0 = (const float*)d_in[6];
  const float* W1 = (const float*)d_in[7];
  const float* b1 = (const float*)d_in[8];
  const float* W2 = (const float*)d_in[9];
  const float* b2 = (const float*)d_in[10];
  const float* g0 = (const float*)d_in[11];
  const float* be0 = (const float*)d_in[12];
  const float* g1 = (const float*)d_in[13];
  const float* be1 = (const float*)d_in[14];
  const float* g2 = (const float*)d_in[15];
  const float* be2 = (const float*)d_in[16];

  int N = in_sizes[0] / DD;
  int E = in_sizes[1] / DD;

  // ws: partial[NBLK*256*64] f32 | cnt[N] int | comb[256*192] bf16
  float* partial = (float*)d_ws;
  int* cnt = (int*)(partial + (size_t)NBLK * 256 * DD);
  ushort* comb = (ushort*)(cnt + N + (N & 1) + 6);  // keep 16B alignment-ish
  // (N=50000 -> cnt ends 16B-aligned already; the +pad guards odd N)

  k_zero<<<64, 256, 0, stream>>>(cnt, N);
  k_hist<<<512, 256, 0, stream>>>(eidx, cnt, E);
  k_edgesum<<<NBLK, 512, 0, stream>>>(edge_attr, eidx, cnt, batch, partial, E);
  k_reduce_pool<<<256, 256, 0, stream>>>(partial, x, u, batch, comb, N);
  k_mlp<<<1, 512, 0, stream>>>(comb, W0, b0, W1, b1, W2, b2,
                               g0, be0, g1, be1, g2, be2, (float*)d_out);
}

// Round 5
// 249.729 us; speedup vs baseline: 1.5218x; 1.5218x over previous
//
#include <hip/hip_runtime.h>
#include <hip/hip_bf16.h>

#define DD 64

typedef __attribute__((ext_vector_type(8))) short bf16x8_t;
typedef __attribute__((ext_vector_type(4))) float f32x4_t;

__device__ __forceinline__ ushort f2b(float x) {
  __hip_bfloat16 h = __float2bfloat16(x);
  ushort r;
  __builtin_memcpy(&r, &h, 2);
  return r;
}

// ---------------------------------------------------------------------------
// Zero cnt.
// ---------------------------------------------------------------------------
__global__ __launch_bounds__(256) void k_zero(int* __restrict__ p, int n) {
  int gid = blockIdx.x * blockDim.x + threadIdx.x;
  int stride = gridDim.x * blockDim.x;
  for (int i = gid; i < n; i += stride) p[i] = 0;
}

// ---------------------------------------------------------------------------
// Histogram of edge destination nodes (int atomics, L2-resident).
// ---------------------------------------------------------------------------
__global__ __launch_bounds__(256) void k_hist(const int* __restrict__ eidx,
                                              int* __restrict__ cnt, int E) {
  int gid = blockIdx.x * blockDim.x + threadIdx.x;
  int stride = gridDim.x * blockDim.x;
  int E4 = E >> 2;
  const int4* e4 = reinterpret_cast<const int4*>(eidx);
  for (int i = gid; i < E4; i += stride) {
    int4 v = e4[i];
    atomicAdd(&cnt[v.x], 1);
    atomicAdd(&cnt[v.y], 1);
    atomicAdd(&cnt[v.z], 1);
    atomicAdd(&cnt[v.w], 1);
  }
  for (int e = (E4 << 2) + gid; e < E; e += stride) atomicAdd(&cnt[eidx[e]], 1);
}

// ---------------------------------------------------------------------------
// Single-block exclusive scan of cnt[N] -> offs[N+1]; cursor[i] = offs[i].
// ---------------------------------------------------------------------------
__global__ __launch_bounds__(1024) void k_scan(const int* __restrict__ cnt,
                                               int* __restrict__ offs,
                                               int* __restrict__ cursor, int N) {
  __shared__ int part[1024];
  int t = threadIdx.x;
  int C = (N + 1023) >> 10;
  int lo = t * C, hi = min(lo + C, N);
  int s = 0;
  for (int i = lo; i < hi; ++i) s += cnt[i];
  part[t] = s;
  __syncthreads();
  for (int off = 1; off < 1024; off <<= 1) {  // Hillis-Steele inclusive scan
    int v = (t >= off) ? part[t - off] : 0;
    __syncthreads();
    part[t] += v;
    __syncthreads();
  }
  int base = part[t] - s;  // exclusive prefix
  for (int i = lo; i < hi; ++i) {
    offs[i] = base;
    cursor[i] = base;
    base += cnt[i];
  }
  if (t == 1023) offs[N] = base;
}

// ---------------------------------------------------------------------------
// Fill CSR records: rec[slot] = {edge id, bits(1/max(cnt[n],1))}.
// One 8B store per edge; slots of one node are contiguous.
// ---------------------------------------------------------------------------
__global__ __launch_bounds__(256) void k_fill(const int* __restrict__ eidx,
                                              const int* __restrict__ cnt,
                                              int* __restrict__ cursor,
                                              int2* __restrict__ rec, int E) {
  int gid = blockIdx.x * blockDim.x + threadIdx.x;
  int stride = gridDim.x * blockDim.x;
  for (int e = gid; e < E; e += stride) {
    int n = eidx[e];
    float w = 1.0f / fmaxf((float)cnt[n], 1.0f);
    int slot = atomicAdd(&cursor[n], 1);
    int2 r;
    r.x = e;
    r.y = __float_as_int(w);
    rec[slot] = r;
  }
}

// ---------------------------------------------------------------------------
// Per-graph fused pooling. batch sorted + CSR node-ordered => graph b's edge
// slots are contiguous [offs[lo_b], offs[hi_b]). One 1024-thread block per
// graph: 64 groups x 16 lanes; register float4 accumulation (no atomics),
// LDS tree reduce; also pools x rows and copies u; writes bf16 comb row.
// ---------------------------------------------------------------------------
__global__ __launch_bounds__(1024) void k_graphpool(const float* __restrict__ edge_attr,
                                                    const int2* __restrict__ rec,
                                                    const int* __restrict__ offs,
                                                    const float* __restrict__ x,
                                                    const float* __restrict__ u,
                                                    const int* __restrict__ batch,
                                                    ushort* __restrict__ comb, int N) {
  __shared__ int s_lo, s_hi;
  __shared__ float rE[64 * 64];
  __shared__ float rV[64 * 64];
  int b = blockIdx.x;
  int tid = threadIdx.x;
  if (tid == 0) {
    int lo = 0, hi = N;
    while (lo < hi) { int m = (lo + hi) >> 1; if (batch[m] < b) lo = m + 1; else hi = m; }
    s_lo = lo;
    hi = N;
    while (lo < hi) { int m = (lo + hi) >> 1; if (batch[m] < b + 1) lo = m + 1; else hi = m; }
    s_hi = lo;
  }
  __syncthreads();
  int lo = s_lo, hi = s_hi;
  int jlo = offs[lo], jhi = offs[hi];
  int g = tid >> 4, lane = tid & 15;

  // edge accumulation: group g handles slots jlo+g, stride 64; unroll x2
  float4 a0 = make_float4(0.f, 0.f, 0.f, 0.f);
  float4 a1 = make_float4(0.f, 0.f, 0.f, 0.f);
  int j = jlo + g;
  for (; j + 64 < jhi; j += 128) {
    int2 r0 = rec[j];
    int2 r1 = rec[j + 64];
    float w0 = __int_as_float(r0.y);
    float w1 = __int_as_float(r1.y);
    const float4 v0 = *reinterpret_cast<const float4*>(edge_attr + (size_t)r0.x * DD + lane * 4);
    const float4 v1 = *reinterpret_cast<const float4*>(edge_attr + (size_t)r1.x * DD + lane * 4);
    a0.x += v0.x * w0; a0.y += v0.y * w0; a0.z += v0.z * w0; a0.w += v0.w * w0;
    a1.x += v1.x * w1; a1.y += v1.y * w1; a1.z += v1.z * w1; a1.w += v1.w * w1;
  }
  if (j < jhi) {
    int2 r0 = rec[j];
    float w0 = __int_as_float(r0.y);
    const float4 v0 = *reinterpret_cast<const float4*>(edge_attr + (size_t)r0.x * DD + lane * 4);
    a0.x += v0.x * w0; a0.y += v0.y * w0; a0.z += v0.z * w0; a0.w += v0.w * w0;
  }
  a0.x += a1.x; a0.y += a1.y; a0.z += a1.z; a0.w += a1.w;

  // x (node) accumulation: sequential rows of this graph
  float4 av = make_float4(0.f, 0.f, 0.f, 0.f);
  for (int n = lo + g; n < hi; n += 64) {
    const float4 v = *reinterpret_cast<const float4*>(x + (size_t)n * DD + lane * 4);
    av.x += v.x; av.y += v.y; av.z += v.z; av.w += v.w;
  }

  *reinterpret_cast<float4*>(&rE[g * 64 + lane * 4]) = a0;
  *reinterpret_cast<float4*>(&rV[g * 64 + lane * 4]) = av;
  __syncthreads();
  if (tid < 64) {
    float sE = 0.f, sV = 0.f;
    for (int gg = 0; gg < 64; ++gg) {
      sE += rE[gg * 64 + tid];
      sV += rV[gg * 64 + tid];
    }
    float invNb = 1.0f / fmaxf((float)(hi - lo), 1.0f);
    ushort* row = comb + (size_t)b * 192;
    row[tid] = f2b(sE * invNb);
    row[64 + tid] = f2b(sV * invNb);
    row[128 + tid] = f2b(u[(size_t)b * DD + tid]);
  }
}

// ---------------------------------------------------------------------------
// MFMA MLP: 1 block, 512 threads (8 waves). Each wave owns 32 rows (2 m-tiles
// of 16) x all 4 n-tiles; K stepped by 32 with mfma_f32_16x16x32_bf16.
// Proven R4 (absmax 0.039 < 0.13).
// ---------------------------------------------------------------------------
template <int K, bool FIRST, bool LAST>
__device__ __forceinline__ void mlp_layer(int tid, const ushort* __restrict__ combg,
                                          float* hbuf, ushort* a_lds, ushort* w_lds,
                                          float* ps, float* pq,
                                          float* bias_s, float* ab, float* bb,
                                          const float* __restrict__ W,
                                          const float* __restrict__ bias,
                                          const float* __restrict__ gamma,
                                          const float* __restrict__ beta,
                                          float* __restrict__ out) {
  const int lane = tid & 63, wv = tid >> 6;
  const int WS = K + 8;  // padded weight row stride (bf16 elems)
  for (int i = tid; i < 64 * K; i += 512) {
    int r = i / K, c = i - r * K;
    w_lds[r * WS + c] = f2b(W[i]);
  }
  if (tid < 64) bias_s[tid] = bias[tid];
  __syncthreads();

  f32x4_t acc[2][4];
#pragma unroll
  for (int a = 0; a < 2; ++a)
#pragma unroll
    for (int nt = 0; nt < 4; ++nt) acc[a][nt] = (f32x4_t)(0.0f);

  const int m0 = wv * 32;
  const int r15 = lane & 15, kq = lane >> 4;
  for (int kk = 0; kk < K; kk += 32) {
    int koff = kk + kq * 8;
    bf16x8_t af[2], bf[4];
    if (FIRST) {
      const ushort* ap = combg + (size_t)(m0 + r15) * 192 + koff;
      af[0] = *reinterpret_cast<const bf16x8_t*>(ap);
      af[1] = *reinterpret_cast<const bf16x8_t*>(ap + 16 * 192);
    } else {
      const ushort* ap = &a_lds[(m0 + r15) * 72 + koff];
      af[0] = *reinterpret_cast<const bf16x8_t*>(ap);
      af[1] = *reinterpret_cast<const bf16x8_t*>(ap + 16 * 72);
    }
#pragma unroll
    for (int nt = 0; nt < 4; ++nt)
      bf[nt] = *reinterpret_cast<const bf16x8_t*>(&w_lds[(nt * 16 + r15) * WS + koff]);
#pragma unroll
    for (int a = 0; a < 2; ++a)
#pragma unroll
      for (int nt = 0; nt < 4; ++nt)
        acc[a][nt] = __builtin_amdgcn_mfma_f32_16x16x32_bf16(af[a], bf[nt], acc[a][nt], 0, 0, 0);
  }

#pragma unroll
  for (int a = 0; a < 2; ++a) {
#pragma unroll
    for (int nt = 0; nt < 4; ++nt) {
      int col = nt * 16 + r15;
#pragma unroll
      for (int j = 0; j < 4; ++j) {
        int row = m0 + a * 16 + kq * 4 + j;
        float v = acc[a][nt][j] + bias_s[col];
        hbuf[row * 65 + col] = fmaxf(v, 0.f);
      }
    }
  }
  __syncthreads();

  {
    int col = tid & 63, seg = tid >> 6;
    float s = 0.f, q = 0.f;
#pragma unroll
    for (int t = 0; t < 32; ++t) {
      float v = hbuf[(seg * 32 + t) * 65 + col];
      s += v;
      q += v * v;
    }
    ps[seg * 64 + col] = s;
    pq[seg * 64 + col] = q;
  }
  __syncthreads();
  if (tid < 64) {
    float s = 0.f, q = 0.f;
#pragma unroll
    for (int g = 0; g < 8; ++g) {
      s += ps[g * 64 + tid];
      q += pq[g * 64 + tid];
    }
    float mu = s * (1.0f / 256.0f);
    float var = q * (1.0f / 256.0f) - mu * mu;
    float rs = rsqrtf(var + 1e-5f);
    float A = gamma[tid] * rs;
    ab[tid] = A;
    bb[tid] = beta[tid] - mu * A;
  }
  __syncthreads();
  for (int i = tid; i < 256 * 64; i += 512) {
    int r = i >> 6, c = i & 63;
    float y = hbuf[r * 65 + c] * ab[c] + bb[c];
    if (LAST)
      out[i] = y;
    else
      a_lds[r * 72 + c] = f2b(y);
  }
  __syncthreads();
}

__global__ __launch_bounds__(512) void k_mlp(const ushort* __restrict__ comb,
                                             const float* W0, const float* b0,
                                             const float* W1, const float* b1,
                                             const float* W2, const float* b2,
                                             const float* g0, const float* be0,
                                             const float* g1, const float* be1,
                                             const float* g2, const float* be2,
                                             float* __restrict__ out) {
  __shared__ __align__(16) float hbuf[256 * 65];    // 66.6 KB
  __shared__ __align__(16) ushort a_lds[256 * 72];  // 36.9 KB
  __shared__ __align__(16) ushort w_lds[64 * 200];  // 25.6 KB (max: K=192)
  __shared__ float ps[8 * 64], pq[8 * 64];
  __shared__ float bias_s[64], ab[64], bb[64];
  int tid = threadIdx.x;
  mlp_layer<192, true, false>(tid, comb, hbuf, a_lds, w_lds, ps, pq, bias_s, ab, bb,
                              W0, b0, g0, be0, nullptr);
  mlp_layer<64, false, false>(tid, comb, hbuf, a_lds, w_lds, ps, pq, bias_s, ab, bb,
                              W1, b1, g1, be1, nullptr);
  mlp_layer<64, false, true>(tid, comb, hbuf, a_lds, w_lds, ps, pq, bias_s, ab, bb,
                             W2, b2, g2, be2, out);
}

extern "C" void kernel_launch(void* const* d_in, const int* in_sizes, int n_in,
                              void* d_out, int out_size, void* d_ws, size_t ws_size,
                              hipStream_t stream) {
  (void)n_in; (void)out_size; (void)ws_size;
  const float* x         = (const float*)d_in[0];
  const float* edge_attr = (const float*)d_in[1];
  const float* u         = (const float*)d_in[2];
  const int*   eidx      = (const int*)d_in[3];  // row 0 = first E entries
  const int*   batch     = (const int*)d_in[4];
  const float* W0 = (const float*)d_in[5];
  const float* b0 = (const float*)d_in[6];
  const float* W1 = (const float*)d_in[7];
  const float* b1 = (const float*)d_in[8];
  const float* W2 = (const float*)d_in[9];
  const float* b2 = (const float*)d_in[10];
  const float* g0 = (const float*)d_in[11];
  const float* be0 = (const float*)d_in[12];
  const float* g1 = (const float*)d_in[13];
  const float* be1 = (const float*)d_in[14];
  const float* g2 = (const float*)d_in[15];
  const float* be2 = (const float*)d_in[16];

  int N = in_sizes[0] / DD;
  int E = in_sizes[1] / DD;
  int B = in_sizes[2] / DD;

  // ws layout (all regions padded to 16B): rec[E] int2 | cnt | offs | cursor | comb
  int2* rec = (int2*)d_ws;
  int* cnt = (int*)(rec + E);
  int* offs = cnt + ((N + 3) & ~3);
  int* cursor = offs + ((N + 1 + 3) & ~3);
  ushort* comb = (ushort*)(cursor + ((N + 3) & ~3));

  k_zero<<<64, 256, 0, stream>>>(cnt, N);
  k_hist<<<1024, 256, 0, stream>>>(eidx, cnt, E);
  k_scan<<<1, 1024, 0, stream>>>(cnt, offs, cursor, N);
  k_fill<<<2048, 256, 0, stream>>>(eidx, cnt, cursor, rec, E);
  k_graphpool<<<B, 1024, 0, stream>>>(edge_attr, rec, offs, x, u, batch, comb, N);
  k_mlp<<<1, 512, 0, stream>>>(comb, W0, b0, W1, b1, W2, b2,
                               g0, be0, g1, be1, g2, be2, (float*)d_out);
}

// Round 6
// 248.816 us; speedup vs baseline: 1.5274x; 1.0037x over previous
//
#include <hip/hip_runtime.h>
#include <hip/hip_bf16.h>

#define DD 64

typedef __attribute__((ext_vector_type(8))) short bf16x8_t;
typedef __attribute__((ext_vector_type(4))) float f32x4_t;

__device__ __forceinline__ ushort f2b(float x) {
  __hip_bfloat16 h = __float2bfloat16(x);
  ushort r;
  __builtin_memcpy(&r, &h, 2);
  return r;
}

// ---------------------------------------------------------------------------
// Zero cnt.
// ---------------------------------------------------------------------------
__global__ __launch_bounds__(256) void k_zero(int* __restrict__ p, int n) {
  int gid = blockIdx.x * blockDim.x + threadIdx.x;
  int stride = gridDim.x * blockDim.x;
  for (int i = gid; i < n; i += stride) p[i] = 0;
}

// ---------------------------------------------------------------------------
// Histogram of edge destination nodes (int atomics, L2-resident).
// ---------------------------------------------------------------------------
__global__ __launch_bounds__(256) void k_hist(const int* __restrict__ eidx,
                                              int* __restrict__ cnt, int E) {
  int gid = blockIdx.x * blockDim.x + threadIdx.x;
  int stride = gridDim.x * blockDim.x;
  int E4 = E >> 2;
  const int4* e4 = reinterpret_cast<const int4*>(eidx);
  for (int i = gid; i < E4; i += stride) {
    int4 v = e4[i];
    atomicAdd(&cnt[v.x], 1);
    atomicAdd(&cnt[v.y], 1);
    atomicAdd(&cnt[v.z], 1);
    atomicAdd(&cnt[v.w], 1);
  }
  for (int e = (E4 << 2) + gid; e < E; e += stride) atomicAdd(&cnt[eidx[e]], 1);
}

// ---------------------------------------------------------------------------
// Single-block exclusive scan of cnt[N] -> offs[N+1]; cursor[i] = offs[i].
// ---------------------------------------------------------------------------
__global__ __launch_bounds__(1024) void k_scan(const int* __restrict__ cnt,
                                               int* __restrict__ offs,
                                               int* __restrict__ cursor, int N) {
  __shared__ int part[1024];
  int t = threadIdx.x;
  int C = (N + 1023) >> 10;
  int lo = t * C, hi = min(lo + C, N);
  int s = 0;
  for (int i = lo; i < hi; ++i) s += cnt[i];
  part[t] = s;
  __syncthreads();
  for (int off = 1; off < 1024; off <<= 1) {  // Hillis-Steele inclusive scan
    int v = (t >= off) ? part[t - off] : 0;
    __syncthreads();
    part[t] += v;
    __syncthreads();
  }
  int base = part[t] - s;  // exclusive prefix
  for (int i = lo; i < hi; ++i) {
    offs[i] = base;
    cursor[i] = base;
    base += cnt[i];
  }
  if (t == 1023) offs[N] = base;
}

// ---------------------------------------------------------------------------
// Fill CSR records: rec[slot] = {edge id, bits(1/max(cnt[n],1))}.
// int4 eidx read -> 4 independent cnt lookups / atomics per thread.
// ---------------------------------------------------------------------------
__device__ __forceinline__ void fill_one(int e, int n, const int* __restrict__ cnt,
                                         int* __restrict__ cursor, int2* __restrict__ rec) {
  float w = 1.0f / fmaxf((float)cnt[n], 1.0f);
  int slot = atomicAdd(&cursor[n], 1);
  int2 r;
  r.x = e;
  r.y = __float_as_int(w);
  rec[slot] = r;
}

__global__ __launch_bounds__(256) void k_fill(const int* __restrict__ eidx,
                                              const int* __restrict__ cnt,
                                              int* __restrict__ cursor,
                                              int2* __restrict__ rec, int E) {
  int gid = blockIdx.x * blockDim.x + threadIdx.x;
  int stride = gridDim.x * blockDim.x;
  int E4 = E >> 2;
  const int4* e4 = reinterpret_cast<const int4*>(eidx);
  for (int i = gid; i < E4; i += stride) {
    int4 v = e4[i];
    int base = i << 2;
    fill_one(base + 0, v.x, cnt, cursor, rec);
    fill_one(base + 1, v.y, cnt, cursor, rec);
    fill_one(base + 2, v.z, cnt, cursor, rec);
    fill_one(base + 3, v.w, cnt, cursor, rec);
  }
  for (int e = (E4 << 2) + gid; e < E; e += stride) fill_one(e, eidx[e], cnt, cursor, rec);
}

// ---------------------------------------------------------------------------
// Per-graph fused pooling. Graph b's edge slots are contiguous
// [offs[lo_b], offs[hi_b]). One 1024-thread block per graph; 64 groups x 16
// lanes. Unroll-8 with batched rec prefetch: 8 gathers in flight per group
// (16 waves x 8 rows x 256B = 32KB in flight per CU >> BW*latency ~9KB) so
// the random-row gather runs BW-bound instead of latency-bound.
// ---------------------------------------------------------------------------
__global__ __launch_bounds__(1024) void k_graphpool(const float* __restrict__ edge_attr,
                                                    const int2* __restrict__ rec,
                                                    const int* __restrict__ offs,
                                                    const float* __restrict__ x,
                                                    const float* __restrict__ u,
                                                    const int* __restrict__ batch,
                                                    ushort* __restrict__ comb, int N) {
  __shared__ int s_lo, s_hi;
  __shared__ float rE[64 * 64];
  __shared__ float rV[64 * 64];
  int b = blockIdx.x;
  int tid = threadIdx.x;
  if (tid == 0) {
    int lo = 0, hi = N;
    while (lo < hi) { int m = (lo + hi) >> 1; if (batch[m] < b) lo = m + 1; else hi = m; }
    s_lo = lo;
    hi = N;
    while (lo < hi) { int m = (lo + hi) >> 1; if (batch[m] < b + 1) lo = m + 1; else hi = m; }
    s_hi = lo;
  }
  __syncthreads();
  int lo = s_lo, hi = s_hi;
  int jlo = offs[lo], jhi = offs[hi];
  int g = tid >> 4, lane = tid & 15;

  float4 a0 = make_float4(0.f, 0.f, 0.f, 0.f);
  float4 a1 = make_float4(0.f, 0.f, 0.f, 0.f);
  int j = jlo + g;
  // main: 8 slots per iteration, all rec loads then all gathers (independent)
  for (; j + 7 * 64 < jhi; j += 8 * 64) {
    int2 r[8];
#pragma unroll
    for (int t = 0; t < 8; ++t) r[t] = rec[j + t * 64];
    float4 v[8];
#pragma unroll
    for (int t = 0; t < 8; ++t)
      v[t] = *reinterpret_cast<const float4*>(edge_attr + (size_t)r[t].x * DD + lane * 4);
#pragma unroll
    for (int t = 0; t < 8; t += 2) {
      float w0 = __int_as_float(r[t].y);
      float w1 = __int_as_float(r[t + 1].y);
      a0.x += v[t].x * w0; a0.y += v[t].y * w0; a0.z += v[t].z * w0; a0.w += v[t].w * w0;
      a1.x += v[t + 1].x * w1; a1.y += v[t + 1].y * w1; a1.z += v[t + 1].z * w1; a1.w += v[t + 1].w * w1;
    }
  }
  // tail
  for (; j < jhi; j += 64) {
    int2 r0 = rec[j];
    float w0 = __int_as_float(r0.y);
    const float4 v0 = *reinterpret_cast<const float4*>(edge_attr + (size_t)r0.x * DD + lane * 4);
    a0.x += v0.x * w0; a0.y += v0.y * w0; a0.z += v0.z * w0; a0.w += v0.w * w0;
  }
  a0.x += a1.x; a0.y += a1.y; a0.z += a1.z; a0.w += a1.w;

  // x (node) accumulation: sequential rows of this graph
  float4 av = make_float4(0.f, 0.f, 0.f, 0.f);
  for (int n = lo + g; n < hi; n += 64) {
    const float4 v = *reinterpret_cast<const float4*>(x + (size_t)n * DD + lane * 4);
    av.x += v.x; av.y += v.y; av.z += v.z; av.w += v.w;
  }

  *reinterpret_cast<float4*>(&rE[g * 64 + lane * 4]) = a0;
  *reinterpret_cast<float4*>(&rV[g * 64 + lane * 4]) = av;
  __syncthreads();
  if (tid < 64) {
    float sE = 0.f, sV = 0.f;
    for (int gg = 0; gg < 64; ++gg) {
      sE += rE[gg * 64 + tid];
      sV += rV[gg * 64 + tid];
    }
    float invNb = 1.0f / fmaxf((float)(hi - lo), 1.0f);
    ushort* row = comb + (size_t)b * 192;
    row[tid] = f2b(sE * invNb);
    row[64 + tid] = f2b(sV * invNb);
    row[128 + tid] = f2b(u[(size_t)b * DD + tid]);
  }
}

// ---------------------------------------------------------------------------
// MFMA MLP: 1 block, 512 threads (8 waves). All three weight matrices +
// biases pre-staged behind ONE barrier (overlapped global latency; removes
// two mid-kernel staging stalls). LDS total ~152.8 KB < 160 KB.
// ---------------------------------------------------------------------------
template <int K, int WS, bool FIRST, bool LAST>
__device__ __forceinline__ void mlp_layer(int tid, const ushort* __restrict__ combg,
                                          float* hbuf, ushort* a_lds,
                                          const ushort* w_lds, const float* bias_s,
                                          float* ps, float* pq, float* ab, float* bb,
                                          const float* __restrict__ gamma,
                                          const float* __restrict__ beta,
                                          float* __restrict__ out) {
  const int lane = tid & 63, wv = tid >> 6;
  f32x4_t acc[2][4];
#pragma unroll
  for (int a = 0; a < 2; ++a)
#pragma unroll
    for (int nt = 0; nt < 4; ++nt) acc[a][nt] = (f32x4_t)(0.0f);

  const int m0 = wv * 32;
  const int r15 = lane & 15, kq = lane >> 4;
  for (int kk = 0; kk < K; kk += 32) {
    int koff = kk + kq * 8;
    bf16x8_t af[2], bf[4];
    if (FIRST) {
      const ushort* ap = combg + (size_t)(m0 + r15) * 192 + koff;
      af[0] = *reinterpret_cast<const bf16x8_t*>(ap);
      af[1] = *reinterpret_cast<const bf16x8_t*>(ap + 16 * 192);
    } else {
      const ushort* ap = &a_lds[(m0 + r15) * 72 + koff];
      af[0] = *reinterpret_cast<const bf16x8_t*>(ap);
      af[1] = *reinterpret_cast<const bf16x8_t*>(ap + 16 * 72);
    }
#pragma unroll
    for (int nt = 0; nt < 4; ++nt)
      bf[nt] = *reinterpret_cast<const bf16x8_t*>(&w_lds[(nt * 16 + r15) * WS + koff]);
#pragma unroll
    for (int a = 0; a < 2; ++a)
#pragma unroll
      for (int nt = 0; nt < 4; ++nt)
        acc[a][nt] = __builtin_amdgcn_mfma_f32_16x16x32_bf16(af[a], bf[nt], acc[a][nt], 0, 0, 0);
  }

#pragma unroll
  for (int a = 0; a < 2; ++a) {
#pragma unroll
    for (int nt = 0; nt < 4; ++nt) {
      int col = nt * 16 + r15;
#pragma unroll
      for (int j = 0; j < 4; ++j) {
        int row = m0 + a * 16 + kq * 4 + j;
        float v = acc[a][nt][j] + bias_s[col];
        hbuf[row * 65 + col] = fmaxf(v, 0.f);
      }
    }
  }
  __syncthreads();

  {
    int col = tid & 63, seg = tid >> 6;
    float s = 0.f, q = 0.f;
#pragma unroll
    for (int t = 0; t < 32; ++t) {
      float v = hbuf[(seg * 32 + t) * 65 + col];
      s += v;
      q += v * v;
    }
    ps[seg * 64 + col] = s;
    pq[seg * 64 + col] = q;
  }
  __syncthreads();
  if (tid < 64) {
    float s = 0.f, q = 0.f;
#pragma unroll
    for (int g = 0; g < 8; ++g) {
      s += ps[g * 64 + tid];
      q += pq[g * 64 + tid];
    }
    float mu = s * (1.0f / 256.0f);
    float var = q * (1.0f / 256.0f) - mu * mu;
    float rs = rsqrtf(var + 1e-5f);
    float A = gamma[tid] * rs;
    ab[tid] = A;
    bb[tid] = beta[tid] - mu * A;
  }
  __syncthreads();
  for (int i = tid; i < 256 * 64; i += 512) {
    int r = i >> 6, c = i & 63;
    float y = hbuf[r * 65 + c] * ab[c] + bb[c];
    if (LAST)
      out[i] = y;
    else
      a_lds[r * 72 + c] = f2b(y);
  }
  __syncthreads();
}

__global__ __launch_bounds__(512) void k_mlp(const ushort* __restrict__ comb,
                                             const float* W0, const float* b0,
                                             const float* W1, const float* b1,
                                             const float* W2, const float* b2,
                                             const float* g0, const float* be0,
                                             const float* g1, const float* be1,
                                             const float* g2, const float* be2,
                                             float* __restrict__ out) {
  __shared__ __align__(16) float hbuf[256 * 65];    // 66.6 KB
  __shared__ __align__(16) ushort a_lds[256 * 72];  // 36.9 KB
  __shared__ __align__(16) ushort w0s[64 * 200];    // 25.6 KB
  __shared__ __align__(16) ushort w1s[64 * 72];     // 9.2 KB
  __shared__ __align__(16) ushort w2s[64 * 72];     // 9.2 KB
  __shared__ float ps[8 * 64], pq[8 * 64];
  __shared__ float b0s[64], b1s[64], b2s[64], ab[64], bb[64];
  int tid = threadIdx.x;

  // stage ALL weights/biases behind one barrier (latencies overlap)
  for (int i = tid; i < 64 * 192; i += 512) {
    int r = i / 192, c = i - r * 192;
    w0s[r * 200 + c] = f2b(W0[i]);
  }
  for (int i = tid; i < 64 * 64; i += 512) {
    int r = i >> 6, c = i & 63;
    w1s[r * 72 + c] = f2b(W1[i]);
    w2s[r * 72 + c] = f2b(W2[i]);
  }
  if (tid < 64) {
    b0s[tid] = b0[tid];
    b1s[tid] = b1[tid];
    b2s[tid] = b2[tid];
  }
  __syncthreads();

  mlp_layer<192, 200, true, false>(tid, comb, hbuf, a_lds, w0s, b0s, ps, pq, ab, bb,
                                   g0, be0, nullptr);
  mlp_layer<64, 72, false, false>(tid, comb, hbuf, a_lds, w1s, b1s, ps, pq, ab, bb,
                                  g1, be1, nullptr);
  mlp_layer<64, 72, false, true>(tid, comb, hbuf, a_lds, w2s, b2s, ps, pq, ab, bb,
                                 g2, be2, out);
}

extern "C" void kernel_launch(void* const* d_in, const int* in_sizes, int n_in,
                              void* d_out, int out_size, void* d_ws, size_t ws_size,
                              hipStream_t stream) {
  (void)n_in; (void)out_size; (void)ws_size;
  const float* x         = (const float*)d_in[0];
  const float* edge_attr = (const float*)d_in[1];
  const float* u         = (const float*)d_in[2];
  const int*   eidx      = (const int*)d_in[3];  // row 0 = first E entries
  const int*   batch     = (const int*)d_in[4];
  const float* W0 = (const float*)d_in[5];
  const float* b0 = (const float*)d_in[6];
  const float* W1 = (const float*)d_in[7];
  const float* b1 = (const float*)d_in[8];
  const float* W2 = (const float*)d_in[9];
  const float* b2 = (const float*)d_in[10];
  const float* g0 = (const float*)d_in[11];
  const float* be0 = (const float*)d_in[12];
  const float* g1 = (const float*)d_in[13];
  const float* be1 = (const float*)d_in[14];
  const float* g2 = (const float*)d_in[15];
  const float* be2 = (const float*)d_in[16];

  int N = in_sizes[0] / DD;
  int E = in_sizes[1] / DD;
  int B = in_sizes[2] / DD;

  // ws layout (16B padded): rec[E] int2 | cnt | offs | cursor | comb
  int2* rec = (int2*)d_ws;
  int* cnt = (int*)(rec + E);
  int* offs = cnt + ((N + 3) & ~3);
  int* cursor = offs + ((N + 1 + 3) & ~3);
  ushort* comb = (ushort*)(cursor + ((N + 3) & ~3));

  k_zero<<<64, 256, 0, stream>>>(cnt, N);
  k_hist<<<1024, 256, 0, stream>>>(eidx, cnt, E);
  k_scan<<<1, 1024, 0, stream>>>(cnt, offs, cursor, N);
  k_fill<<<2048, 256, 0, stream>>>(eidx, cnt, cursor, rec, E);
  k_graphpool<<<B, 1024, 0, stream>>>(edge_attr, rec, offs, x, u, batch, comb, N);
  k_mlp<<<1, 512, 0, stream>>>(comb, W0, b0, W1, b1, W2, b2,
                               g0, be0, g1, be1, g2, be2, (float*)d_out);
}